// Round 1
// baseline (321.775 us; speedup 1.0000x reference)
//
#include <hip/hip_runtime.h>

#define NROWS 8192
#define DDIM  256
#define BM    128
#define BN    128
#define BK    64

typedef __attribute__((ext_vector_type(8))) short bf16x8;
typedef __attribute__((ext_vector_type(4))) float f32x4;

// round-to-nearest-even f32 -> bf16 bits (inputs are finite gaussians; no NaN path)
static __device__ __forceinline__ unsigned short f2bf(float f) {
    unsigned u = __float_as_uint(f);
    u += 0x7fff + ((u >> 16) & 1);
    return (unsigned short)(u >> 16);
}

// Pass 1: f32 -> bf16 conversion + per-row sum of squares.
// One wave per row (256 f32 = 64 lanes x float4).
__global__ __launch_bounds__(256) void rbf_prep_kernel(
    const float* __restrict__ x, const float* __restrict__ y,
    unsigned short* __restrict__ xb, unsigned short* __restrict__ yb,
    float* __restrict__ xsq, float* __restrict__ ysq)
{
    const int lane = threadIdx.x & 63;
    const int wid  = threadIdx.x >> 6;
    int row = blockIdx.x * 4 + wid;            // 0..16383
    const float* src; unsigned short* dst; float* sq; int r;
    if (row < NROWS) { src = x; dst = xb; sq = xsq; r = row; }
    else             { src = y; dst = yb; sq = ysq; r = row - NROWS; }

    const float4 v = ((const float4*)(src + (size_t)r * DDIM))[lane];
    ushort4 b;
    b.x = f2bf(v.x); b.y = f2bf(v.y); b.z = f2bf(v.z); b.w = f2bf(v.w);
    ((ushort4*)(dst + (size_t)r * DDIM))[lane] = b;

    float s = v.x * v.x + v.y * v.y + v.z * v.z + v.w * v.w;
    #pragma unroll
    for (int o = 32; o > 0; o >>= 1) s += __shfl_down(s, o);
    if (lane == 0) sq[r] = s;
}

// Pass 2: C = Xb * Yb^T via bf16 MFMA, epilogue exp(-(xsq + ysq - 2C)).
// 128x128 tile, BK=64, 4 waves in 2x2, global_load_lds width-16 staging.
__global__ __launch_bounds__(256) void rbf_gemm_kernel(
    const unsigned short* __restrict__ A,   // 8192 x 256 bf16 (X)
    const unsigned short* __restrict__ B,   // 8192 x 256 bf16 (Y), row-major = B^T layout
    const float* __restrict__ xsq, const float* __restrict__ ysq,
    float* __restrict__ out)
{
    __shared__ unsigned short As[BM * BK];
    __shared__ unsigned short Bs[BN * BK];

    const int t    = threadIdx.x;
    const int lane = t & 63;
    const int wid  = t >> 6;
    const int wr   = wid >> 1;          // wave row (0..1) -> 64-row slab
    const int wc   = wid & 1;           // wave col (0..1) -> 64-col slab
    const int brow = blockIdx.y * BM;
    const int bcol = blockIdx.x * BN;

    f32x4 acc[4][4] = {};               // 4x4 fragments of 16x16

    const int rr = lane & 15;           // row within fragment (A) / col (B)
    const int kq = lane >> 4;           // k-quarter

    for (int kt = 0; kt < DDIM; kt += BK) {
        // stage A-tile [128][64] and B-tile [128][64] (row-major, linear in lane order)
        #pragma unroll
        for (int i = 0; i < 4; ++i) {
            const int idx = (i * 256 + t) * 8;      // element index in tile
            const int r   = idx >> 6;               // tile row
            const int c   = idx & 63;               // tile col (k)
            __builtin_amdgcn_global_load_lds(
                (const __attribute__((address_space(1))) unsigned int*)(A + (size_t)(brow + r) * DDIM + kt + c),
                (__attribute__((address_space(3))) unsigned int*)(As + idx), 16, 0, 0);
            __builtin_amdgcn_global_load_lds(
                (const __attribute__((address_space(1))) unsigned int*)(B + (size_t)(bcol + r) * DDIM + kt + c),
                (__attribute__((address_space(3))) unsigned int*)(Bs + idx), 16, 0, 0);
        }
        __syncthreads();   // compiler drains vmcnt(0) before s_barrier

        #pragma unroll
        for (int ks = 0; ks < 2; ++ks) {
            bf16x8 a[4], b[4];
            const int ko = ks * 32 + kq * 8;
            #pragma unroll
            for (int m = 0; m < 4; ++m)
                a[m] = *(const bf16x8*)(As + (wr * 64 + m * 16 + rr) * BK + ko);
            #pragma unroll
            for (int n = 0; n < 4; ++n)
                b[n] = *(const bf16x8*)(Bs + (wc * 64 + n * 16 + rr) * BK + ko);
            #pragma unroll
            for (int m = 0; m < 4; ++m)
                #pragma unroll
                for (int n = 0; n < 4; ++n)
                    acc[m][n] = __builtin_amdgcn_mfma_f32_16x16x32_bf16(a[m], b[n], acc[m][n], 0, 0, 0);
        }
        __syncthreads();
    }

    // epilogue: C/D layout col = lane&15, row = (lane>>4)*4 + reg  [m89-verified]
    const int cl = lane & 15;
    const int rq = lane >> 4;
    #pragma unroll
    for (int n = 0; n < 4; ++n) {
        const int col = bcol + wc * 64 + n * 16 + cl;
        const float ysv = ysq[col];
        #pragma unroll
        for (int m = 0; m < 4; ++m) {
            const int row0 = brow + wr * 64 + m * 16 + rq * 4;
            #pragma unroll
            for (int r2 = 0; r2 < 4; ++r2) {
                const int row = row0 + r2;
                float d = xsq[row] + ysv - 2.0f * acc[m][n][r2];
                d = fmaxf(d, 0.0f);
                out[(size_t)row * NROWS + col] = __expf(-d);
            }
        }
    }
}

extern "C" void kernel_launch(void* const* d_in, const int* in_sizes, int n_in,
                              void* d_out, int out_size, void* d_ws, size_t ws_size,
                              hipStream_t stream) {
    const float* x = (const float*)d_in[0];
    const float* y = (const float*)d_in[1];
    float* out = (float*)d_out;

    // ws layout: xb (4 MiB) | yb (4 MiB) | xsq (32 KiB) | ysq (32 KiB)  -> ~8.45 MB
    unsigned short* xb = (unsigned short*)d_ws;
    unsigned short* yb = xb + (size_t)NROWS * DDIM;
    float* xsq = (float*)(yb + (size_t)NROWS * DDIM);
    float* ysq = xsq + NROWS;

    rbf_prep_kernel<<<dim3((2 * NROWS) / 4), 256, 0, stream>>>(x, y, xb, yb, xsq, ysq);
    rbf_gemm_kernel<<<dim3(NROWS / BN, NROWS / BM), 256, 0, stream>>>(xb, yb, xsq, ysq, out);
}

// Round 2
// 310.286 us; speedup vs baseline: 1.0370x; 1.0370x over previous
//
#include <hip/hip_runtime.h>

#define NROWS 8192
#define DDIM  256
#define BM    128
#define BN    128
#define BK    64

typedef __attribute__((ext_vector_type(8))) short bf16x8;
typedef __attribute__((ext_vector_type(4))) float f32x4;

// round-to-nearest-even f32 -> bf16 bits (inputs are finite gaussians; no NaN path)
static __device__ __forceinline__ unsigned short f2bf(float f) {
    unsigned u = __float_as_uint(f);
    u += 0x7fff + ((u >> 16) & 1);
    return (unsigned short)(u >> 16);
}

// Pass 1: f32 -> bf16 conversion + per-row sum of squares.
// One wave per row (256 f32 = 64 lanes x float4).
__global__ __launch_bounds__(256) void rbf_prep_kernel(
    const float* __restrict__ x, const float* __restrict__ y,
    unsigned short* __restrict__ xb, unsigned short* __restrict__ yb,
    float* __restrict__ xsq, float* __restrict__ ysq)
{
    const int lane = threadIdx.x & 63;
    const int wid  = threadIdx.x >> 6;
    int row = blockIdx.x * 4 + wid;            // 0..16383
    const float* src; unsigned short* dst; float* sq; int r;
    if (row < NROWS) { src = x; dst = xb; sq = xsq; r = row; }
    else             { src = y; dst = yb; sq = ysq; r = row - NROWS; }

    const float4 v = ((const float4*)(src + (size_t)r * DDIM))[lane];
    ushort4 b;
    b.x = f2bf(v.x); b.y = f2bf(v.y); b.z = f2bf(v.z); b.w = f2bf(v.w);
    ((ushort4*)(dst + (size_t)r * DDIM))[lane] = b;

    float s = v.x * v.x + v.y * v.y + v.z * v.z + v.w * v.w;
    #pragma unroll
    for (int o = 32; o > 0; o >>= 1) s += __shfl_down(s, o);
    if (lane == 0) sq[r] = s;
}

// Pass 2: C = Xb * Yb^T via bf16 MFMA, epilogue exp(-(xsq + ysq - 2C)).
// 128x128 tile, BK=64, 4 waves in 2x2, global_load_lds width-16 staging.
// MFMA operands are SWAPPED (mfma(b,a)) so the C/D fragment is transposed:
//   lane holds row = lane&15 (X index), cols = (lane>>4)*4 + reg (Y index)
// -> each lane owns 4 consecutive output COLUMNS of one row => float4 stores.
__global__ __launch_bounds__(256) void rbf_gemm_kernel(
    const unsigned short* __restrict__ A,   // 8192 x 256 bf16 (X)
    const unsigned short* __restrict__ B,   // 8192 x 256 bf16 (Y), row-major
    const float* __restrict__ xsq, const float* __restrict__ ysq,
    float* __restrict__ out)
{
    __shared__ unsigned short As[BM * BK];
    __shared__ unsigned short Bs[BN * BK];

    const int t    = threadIdx.x;
    const int lane = t & 63;
    const int wid  = t >> 6;
    const int wr   = wid >> 1;          // wave row (0..1) -> 64-row slab of X
    const int wc   = wid & 1;           // wave col (0..1) -> 64-col slab of Y
    const int brow = blockIdx.y * BM;
    const int bcol = blockIdx.x * BN;

    f32x4 acc[4][4] = {};               // [m][n] transposed 16x16 fragments

    const int rr = lane & 15;           // row within fragment (both operands)
    const int kq = lane >> 4;           // k-quarter

    for (int kt = 0; kt < DDIM; kt += BK) {
        // stage A-tile [128][64] and B-tile [128][64] (row-major, linear lane order)
        #pragma unroll
        for (int i = 0; i < 4; ++i) {
            const int idx = (i * 256 + t) * 8;      // element index in tile
            const int r   = idx >> 6;               // tile row
            const int c   = idx & 63;               // tile col (k)
            __builtin_amdgcn_global_load_lds(
                (const __attribute__((address_space(1))) unsigned int*)(A + (size_t)(brow + r) * DDIM + kt + c),
                (__attribute__((address_space(3))) unsigned int*)(As + idx), 16, 0, 0);
            __builtin_amdgcn_global_load_lds(
                (const __attribute__((address_space(1))) unsigned int*)(B + (size_t)(bcol + r) * DDIM + kt + c),
                (__attribute__((address_space(3))) unsigned int*)(Bs + idx), 16, 0, 0);
        }
        __syncthreads();

        #pragma unroll
        for (int ks = 0; ks < 2; ++ks) {
            bf16x8 a[4], b[4];
            const int ko = ks * 32 + kq * 8;
            #pragma unroll
            for (int m = 0; m < 4; ++m)
                a[m] = *(const bf16x8*)(As + (wr * 64 + m * 16 + rr) * BK + ko);
            #pragma unroll
            for (int n = 0; n < 4; ++n)
                b[n] = *(const bf16x8*)(Bs + (wc * 64 + n * 16 + rr) * BK + ko);
            #pragma unroll
            for (int m = 0; m < 4; ++m)
                #pragma unroll
                for (int n = 0; n < 4; ++n)
                    acc[m][n] = __builtin_amdgcn_mfma_f32_16x16x32_bf16(b[n], a[m], acc[m][n], 0, 0, 0);
        }
        __syncthreads();
    }

    // epilogue: transposed fragment => lane's X row = lane&15, Y cols = rq*4+{0..3}
    const int cl = lane & 15;
    const int rq = lane >> 4;
    #pragma unroll
    for (int m = 0; m < 4; ++m) {
        const int row = brow + wr * 64 + m * 16 + cl;
        const float xsv = xsq[row];
        float* orow = out + (size_t)row * NROWS;
        #pragma unroll
        for (int n = 0; n < 4; ++n) {
            const int col = bcol + wc * 64 + n * 16 + rq * 4;
            const float4 ysv = *(const float4*)(ysq + col);
            float4 o;
            o.x = __expf(-fmaxf(xsv + ysv.x - 2.0f * acc[m][n][0], 0.0f));
            o.y = __expf(-fmaxf(xsv + ysv.y - 2.0f * acc[m][n][1], 0.0f));
            o.z = __expf(-fmaxf(xsv + ysv.z - 2.0f * acc[m][n][2], 0.0f));
            o.w = __expf(-fmaxf(xsv + ysv.w - 2.0f * acc[m][n][3], 0.0f));
            *(float4*)(orow + col) = o;
        }
    }
}

extern "C" void kernel_launch(void* const* d_in, const int* in_sizes, int n_in,
                              void* d_out, int out_size, void* d_ws, size_t ws_size,
                              hipStream_t stream) {
    const float* x = (const float*)d_in[0];
    const float* y = (const float*)d_in[1];
    float* out = (float*)d_out;

    // ws layout: xb (4 MiB) | yb (4 MiB) | xsq (32 KiB) | ysq (32 KiB)
    unsigned short* xb = (unsigned short*)d_ws;
    unsigned short* yb = xb + (size_t)NROWS * DDIM;
    float* xsq = (float*)(yb + (size_t)NROWS * DDIM);
    float* ysq = xsq + NROWS;

    rbf_prep_kernel<<<dim3((2 * NROWS) / 4), 256, 0, stream>>>(x, y, xb, yb, xsq, ysq);
    rbf_gemm_kernel<<<dim3(NROWS / BN, NROWS / BM), 256, 0, stream>>>(xb, yb, xsq, ysq, out);
}